// Round 6
// baseline (1357.533 us; speedup 1.0000x reference)
//
#include <hip/hip_runtime.h>

#define BB 8
#define TIN 168
#define NN 1500
#define TOUTC 24
#define TLEN 162
#define NG 32
#define NTH 768
#define SN 2
#define TOPKK 12

// workspace offsets (in 4-byte elements)
#define OFF_M1   0
#define OFF_M2   24000
#define OFF_EW   48000
#define OFF_EB   48112
#define OFF_ADJW 48128
#define OFF_ADJI 67628
#define OFF_PART 87136
// part is [b][g][c=16][v] : 8*32*16*1500 floats = 24.58 MB
// total ws need: (87136 + 6144000)*4 = 24,924,544 bytes

__device__ __forceinline__ unsigned short f2bf(float f) {
    unsigned int u = __float_as_uint(f);
    unsigned int r = (u + 0x7fffu + ((u >> 16) & 1u)) >> 16;
    return (unsigned short)r;
}
__device__ __forceinline__ unsigned int pack2(float lo, float hi) {
    return (unsigned int)f2bf(lo) | ((unsigned int)f2bf(hi) << 16);
}
__device__ __forceinline__ float unlo(unsigned int u) { return __uint_as_float(u << 16); }
__device__ __forceinline__ float unhi(unsigned int u) { return __uint_as_float(u & 0xffff0000u); }

// ---------------- prep: m1/m2 embeddings + effective inception taps ----------------
__global__ __launch_bounds__(256) void prep_kernel(
    const float* __restrict__ e1, const float* __restrict__ e2,
    const float* __restrict__ gw1, const float* __restrict__ gb1,
    const float* __restrict__ gw2, const float* __restrict__ gb2,
    const float* __restrict__ pw, const float* __restrict__ pb,
    const float* __restrict__ tw2, const float* __restrict__ tb2,
    const float* __restrict__ tw3, const float* __restrict__ tb3,
    const float* __restrict__ tw6, const float* __restrict__ tb6,
    const float* __restrict__ tw7, const float* __restrict__ tb7,
    float* __restrict__ ws)
{
    int n = blockIdx.x * blockDim.x + threadIdx.x;
    if (n < NN) {
        float a1[16], a2[16];
        #pragma unroll
        for (int o = 0; o < 16; ++o) { a1[o] = gb1[o]; a2[o] = gb2[o]; }
        #pragma unroll
        for (int i = 0; i < 16; ++i) {
            float u = e1[n*16+i], v = e2[n*16+i];
            #pragma unroll
            for (int o = 0; o < 16; ++o) {
                a1[o] += u * gw1[i*16+o];
                a2[o] += v * gw2[i*16+o];
            }
        }
        #pragma unroll
        for (int o = 0; o < 16; ++o) {
            ws[OFF_M1 + n*16+o] = tanhf(1.5f*a1[o]);
            ws[OFF_M2 + n*16+o] = tanhf(1.5f*a2[o]);
        }
    }
    if (blockIdx.x == 0 && threadIdx.x < 16) {
        int c = threadIdx.x;
        int br = c >> 2, oc = c & 3;
        const float* tw; const float* tb; int k;
        if (br == 0)      { tw = tw2; tb = tb2; k = 2; }
        else if (br == 1) { tw = tw3; tb = tb3; k = 3; }
        else if (br == 2) { tw = tw6; tb = tb6; k = 6; }
        else              { tw = tw7; tb = tb7; k = 7; }
        for (int d = 0; d < 7; ++d) ws[OFF_EW + c*7 + d] = 0.f;
        float ebv = tb[oc];
        for (int j = 0; j < k; ++j) {
            float s = 0.f, sb = 0.f;
            for (int ic = 0; ic < 16; ++ic) {
                float w = tw[(oc*16+ic)*k + j];
                s  += w * pw[ic];
                sb += w * pb[ic];
            }
            ws[OFF_EW + c*7 + (7-k+j)] = s;
            ebv += sb;
        }
        ws[OFF_EB + c] = ebv;
    }
}

// ---------------- graph: scores in registers + shuffle-argmax top-12 ----------------
// Each thread owns 6 strided score elements (registers). Per top-k iter:
// shuffle-reduce the per-thread argmax, owner rescans its 6. 2 barriers/iter.
__global__ __launch_bounds__(256) void graph_kernel(
    const float* __restrict__ m1, const float* __restrict__ m2,
    float* __restrict__ adjw, int* __restrict__ adji)
{
    int v = blockIdx.x;
    int tid = threadIdx.x;
    __shared__ float wv4[4];
    __shared__ int   wi4[4];
    __shared__ int   bcast_i;
    __shared__ float m1v[16], m2v[16];
    if (tid < 16) { m1v[tid] = m1[v*16+tid]; m2v[tid] = m2[v*16+tid]; }
    __syncthreads();
    const float4* m1f = (const float4*)m1;
    const float4* m2f = (const float4*)m2;
    float sreg[6];
    #pragma unroll
    for (int u = 0; u < 6; ++u) {
        int j = tid + 256*u;
        float a = -1.f;
        if (j < NN) {
            float d = 0.f;
            #pragma unroll
            for (int q = 0; q < 4; ++q) {
                float4 r2 = m2f[j*4+q];
                float4 r1 = m1f[j*4+q];
                d += m1v[4*q+0]*r2.x - m2v[4*q+0]*r1.x;
                d += m1v[4*q+1]*r2.y - m2v[4*q+1]*r1.y;
                d += m1v[4*q+2]*r2.z - m2v[4*q+2]*r1.z;
                d += m1v[4*q+3]*r2.w - m2v[4*q+3]*r1.w;
            }
            float t = tanhf(1.5f*d);
            a = t > 0.f ? t : 0.f;
        }
        sreg[u] = a;
    }
    // per-thread local argmax (ascending u => lowest index on ties via strict >)
    float lb = -1.f; int li = NN;
    #pragma unroll
    for (int u = 0; u < 6; ++u) {
        int j = tid + 256*u;
        if (j < NN && sreg[u] > lb) { lb = sreg[u]; li = j; }
    }
    const int wid = tid >> 6;
    for (int it = 0; it < TOPKK; ++it) {
        float bv = lb; int bi = li;
        #pragma unroll
        for (int off = 32; off > 0; off >>= 1) {
            float ov = __shfl_down(bv, off);
            int   oi = __shfl_down(bi, off);
            if (ov > bv || (ov == bv && oi < bi)) { bv = ov; bi = oi; }
        }
        if ((tid & 63) == 0) { wv4[wid] = bv; wi4[wid] = bi; }
        __syncthreads();
        if (tid == 0) {
            #pragma unroll
            for (int w = 1; w < 4; ++w) {
                float ov = wv4[w]; int oi = wi4[w];
                if (ov > bv || (ov == bv && oi < bi)) { bv = ov; bi = oi; }
            }
            adjw[v*13+it] = bv;
            adji[v*13+it] = bi;
            bcast_i = bi;
        }
        __syncthreads();
        int win = bcast_i;
        if (li == win) {   // owner (stripes disjoint -> unique owner) removes + rescans
            #pragma unroll
            for (int u = 0; u < 6; ++u)
                if (tid + 256*u == win) sreg[u] = -1.f;
            lb = -1.f; li = NN;
            #pragma unroll
            for (int u = 0; u < 6; ++u) {
                int j = tid + 256*u;
                if (j < NN && sreg[u] > lb) { lb = sreg[u]; li = j; }
            }
        }
    }
    if (tid == 0) {
        float s = 1.f;
        #pragma unroll
        for (int it = 0; it < TOPKK; ++it) s += adjw[v*13+it];
        float inv = 1.f/s;
        #pragma unroll
        for (int it = 0; it < TOPKK; ++it) adjw[v*13+it] *= inv;
        adji[v*13+12] = v;
        adjw[v*13+12] = inv;   // normalized self-loop
    }
}

// gather: hp = 0.2*own(h1) + 0.8 * sum_j w_j * src[nb_j]  -> dst (all bf16 LDS)
__device__ __forceinline__ void mixhop_gather(
    const uint4* own0, const uint4* own1,
    const uint4* src0, const uint4* src1,
    uint4* dst0, uint4* dst1,
    int v, const int* __restrict__ adji, const float* __restrict__ adjw)
{
    float hp[16];
    {
        uint4 a0 = own0[v], a1 = own1[v];
        unsigned int uu[8] = {a0.x,a0.y,a0.z,a0.w,a1.x,a1.y,a1.z,a1.w};
        #pragma unroll
        for (int i = 0; i < 8; ++i) { hp[2*i] = 0.2f*unlo(uu[i]); hp[2*i+1] = 0.2f*unhi(uu[i]); }
    }
    int base = v*13;
    #pragma unroll
    for (int j = 0; j < 13; ++j) {
        int nb = adji[base+j];
        float w = 0.8f*adjw[base+j];
        uint4 b0 = src0[nb], b1 = src1[nb];
        unsigned int uu[8] = {b0.x,b0.y,b0.z,b0.w,b1.x,b1.y,b1.z,b1.w};
        #pragma unroll
        for (int i = 0; i < 8; ++i) { hp[2*i] += w*unlo(uu[i]); hp[2*i+1] += w*unhi(uu[i]); }
    }
    dst0[v] = make_uint4(pack2(hp[0],hp[1]), pack2(hp[2],hp[3]), pack2(hp[4],hp[5]), pack2(hp[6],hp[7]));
    dst1[v] = make_uint4(pack2(hp[8],hp[9]), pack2(hp[10],hp[11]), pack2(hp[12],hp[13]), pack2(hp[14],hp[15]));
}

// ---------------- main: 4 phases/t, all slices bf16 in LDS, minimal live regs ----------------
__global__ __launch_bounds__(NTH, 3) void main_kernel(
    const float* __restrict__ x,
    const float* __restrict__ ew, const float* __restrict__ eb,
    const float* __restrict__ adjw, const int* __restrict__ adji,
    float* __restrict__ part,
    const float* __restrict__ mw, const float* __restrict__ mb,
    const float* __restrict__ rw1, const float* __restrict__ rb1)
{
    // SoA by row: row r holds channels 8r..8r+7 (uint4 = 8 bf16), contiguous in v.
    __shared__ uint4 h1b[2][NN];   // 48000 B : h1
    __shared__ uint4 p1b[2][NN];   // 48000 B : hop1
    __shared__ uint4 p2b[2][NN];   // 48000 B : hop2

    const int tid = threadIdx.x;
    const int b = blockIdx.x >> 5;
    const int g = blockIdx.x & 31;
    const int t0 = (g*TLEN) >> 5;
    const int t1 = ((g+1)*TLEN) >> 5;

    float racc[SN][16];
    #pragma unroll
    for (int s = 0; s < SN; ++s)
        #pragma unroll
        for (int o = 0; o < 16; ++o) racc[s][o] = 0.f;

    for (int t = t0; t < t1; ++t) {
        // ---- Phase A: 7-tap conv -> h1 (bf16) ----
        #pragma unroll
        for (int s = 0; s < SN; ++s) {
            int v = tid + NTH*s;
            if (v < NN) {
                float xv[7];
                #pragma unroll
                for (int d = 0; d < 7; ++d) xv[d] = x[(b*TIN + t + d)*NN + v];
                float h[16];
                #pragma unroll
                for (int c = 0; c < 16; ++c) {
                    float a = eb[c];
                    #pragma unroll
                    for (int d = 0; d < 7; ++d) a += ew[c*7+d]*xv[d];
                    h[c] = a > 0.f ? a : 0.f;
                }
                h1b[0][v] = make_uint4(pack2(h[0],h[1]), pack2(h[2],h[3]), pack2(h[4],h[5]), pack2(h[6],h[7]));
                h1b[1][v] = make_uint4(pack2(h[8],h[9]), pack2(h[10],h[11]), pack2(h[12],h[13]), pack2(h[14],h[15]));
            }
        }
        __syncthreads();
        // ---- Phase B: hop1 = 0.2*h1own + 0.8*A@h1 ----
        #pragma unroll
        for (int s = 0; s < SN; ++s) {
            int v = tid + NTH*s;
            if (v < NN)
                mixhop_gather(h1b[0], h1b[1], h1b[0], h1b[1], p1b[0], p1b[1], v, adji, adjw);
        }
        __syncthreads();
        // ---- Phase C: hop2 = 0.2*h1own + 0.8*A@hop1 ----
        #pragma unroll
        for (int s = 0; s < SN; ++s) {
            int v = tid + NTH*s;
            if (v < NN)
                mixhop_gather(h1b[0], h1b[1], p1b[0], p1b[1], p2b[0], p2b[1], v, adji, adjw);
        }
        __syncthreads();
        // ---- Phase D: y16 = mb + mw@[h1;hop1;hop2] ; relu ; rw1 ; racc += relu ----
        #pragma unroll
        for (int s = 0; s < SN; ++s) {
            int v = tid + NTH*s;
            if (v < NN) {
                float y16[16];
                #pragma unroll
                for (int o = 0; o < 16; ++o) y16[o] = mb[o];

                #define FOLD_REGION(B0, B1, OFFC)  { \
                    uint4 a0 = (B0)[v], a1 = (B1)[v]; \
                    unsigned int uu[8] = {a0.x,a0.y,a0.z,a0.w,a1.x,a1.y,a1.z,a1.w}; \
                    _Pragma("unroll") \
                    for (int i = 0; i < 8; ++i) { \
                        float f0 = unlo(uu[i]), f1 = unhi(uu[i]); \
                        _Pragma("unroll") \
                        for (int o = 0; o < 16; ++o) \
                            y16[o] += mw[o*48 + (OFFC) + 2*i]*f0 + mw[o*48 + (OFFC) + 2*i+1]*f1; \
                    } }

                FOLD_REGION(h1b[0], h1b[1], 0)
                FOLD_REGION(p1b[0], p1b[1], 16)
                FOLD_REGION(p2b[0], p2b[1], 32)
                #undef FOLD_REGION

                #pragma unroll
                for (int o = 0; o < 16; ++o) y16[o] = y16[o] > 0.f ? y16[o] : 0.f;
                #pragma unroll
                for (int o = 0; o < 16; ++o) {
                    float a = rb1[o];
                    #pragma unroll
                    for (int i = 0; i < 16; ++i) a += rw1[o*16+i]*y16[i];
                    racc[s][o] += (a > 0.f ? a : 0.f);
                }
            }
        }
        __syncthreads();   // D reads h1b/p1b/p2b; next-t A overwrites h1b
    }
    #pragma unroll
    for (int s = 0; s < SN; ++s) {
        int v = tid + NTH*s;
        if (v < NN) {
            #pragma unroll
            for (int o = 0; o < 16; ++o)
                part[((b*NG + g)*16 + o)*NN + v] = racc[s][o];
        }
    }
}

// ---------------- reduce: sum 32 t-group racc partials, apply rw2/rb2, mean ----------------
__global__ __launch_bounds__(256) void reduce_kernel(const float* __restrict__ part,
                                                     const float* __restrict__ rw2,
                                                     const float* __restrict__ rb2,
                                                     float* __restrict__ out)
{
    int idx = blockIdx.x*256 + threadIdx.x;   // idx over b*NN + v
    if (idx >= BB*NN) return;
    int v = idx % NN;
    int b = idx / NN;
    float s16[16];
    #pragma unroll
    for (int c = 0; c < 16; ++c) s16[c] = 0.f;
    for (int g = 0; g < NG; ++g) {
        #pragma unroll
        for (int c = 0; c < 16; ++c)
            s16[c] += part[((b*NG + g)*16 + c)*NN + v];
    }
    #pragma unroll
    for (int c = 0; c < 16; ++c) s16[c] *= (1.0f/TLEN);
    #pragma unroll
    for (int o = 0; o < TOUTC; ++o) {
        float a = rb2[o];
        #pragma unroll
        for (int c = 0; c < 16; ++c) a += rw2[o*16+c]*s16[c];
        out[(b*TOUTC + o)*NN + v] = a;
    }
}

extern "C" void kernel_launch(void* const* d_in, const int* in_sizes, int n_in,
                              void* d_out, int out_size, void* d_ws, size_t ws_size,
                              hipStream_t stream)
{
    const float* x   = (const float*)d_in[0];
    const float* pw  = (const float*)d_in[1];
    const float* pb  = (const float*)d_in[2];
    const float* tw2 = (const float*)d_in[3];
    const float* tb2 = (const float*)d_in[4];
    const float* tw3 = (const float*)d_in[5];
    const float* tb3 = (const float*)d_in[6];
    const float* tw6 = (const float*)d_in[7];
    const float* tb6 = (const float*)d_in[8];
    const float* tw7 = (const float*)d_in[9];
    const float* tb7 = (const float*)d_in[10];
    const float* e1  = (const float*)d_in[11];
    const float* e2  = (const float*)d_in[12];
    const float* gw1 = (const float*)d_in[13];
    const float* gb1 = (const float*)d_in[14];
    const float* gw2 = (const float*)d_in[15];
    const float* gb2 = (const float*)d_in[16];
    const float* mw  = (const float*)d_in[17];
    const float* mb  = (const float*)d_in[18];
    const float* rw1 = (const float*)d_in[19];
    const float* rb1 = (const float*)d_in[20];
    const float* rw2 = (const float*)d_in[21];
    const float* rb2 = (const float*)d_in[22];
    float* ws  = (float*)d_ws;
    float* out = (float*)d_out;

    prep_kernel<<<(NN + 255)/256, 256, 0, stream>>>(e1,e2,gw1,gb1,gw2,gb2,pw,pb,
                                                    tw2,tb2,tw3,tb3,tw6,tb6,tw7,tb7, ws);
    graph_kernel<<<NN, 256, 0, stream>>>(ws + OFF_M1, ws + OFF_M2,
                                         ws + OFF_ADJW, (int*)ws + OFF_ADJI);
    main_kernel<<<BB*NG, NTH, 0, stream>>>(x, ws + OFF_EW, ws + OFF_EB,
                                           ws + OFF_ADJW, (const int*)ws + OFF_ADJI,
                                           ws + OFF_PART, mw, mb, rw1, rb1);
    reduce_kernel<<<(BB*NN + 255)/256, 256, 0, stream>>>(ws + OFF_PART, rw2, rb2, out);
}

// Round 7
// 650.299 us; speedup vs baseline: 2.0876x; 2.0876x over previous
//
#include <hip/hip_runtime.h>

#define BB 8
#define TIN 168
#define NN 1500
#define TOUTC 24
#define TLEN 162
#define NG 32
#define NTH 768
#define SN 2
#define TOPKK 12

// workspace offsets (in 4-byte elements)
#define OFF_M1   0
#define OFF_M2   24000
#define OFF_EW   48000
#define OFF_EB   48112
#define OFF_ADJW 48128
#define OFF_ADJI 67628
#define OFF_PART 87136
// part is [b][g][c=16][v] : 8*32*16*1500 floats = 24.58 MB
// total ws need: (87136 + 6144000)*4 = 24,924,544 bytes

__device__ __forceinline__ unsigned short f2bf(float f) {
    unsigned int u = __float_as_uint(f);
    unsigned int r = (u + 0x7fffu + ((u >> 16) & 1u)) >> 16;
    return (unsigned short)r;
}
__device__ __forceinline__ unsigned int pack2(float lo, float hi) {
    return (unsigned int)f2bf(lo) | ((unsigned int)f2bf(hi) << 16);
}
__device__ __forceinline__ float unlo(unsigned int u) { return __uint_as_float(u << 16); }
__device__ __forceinline__ float unhi(unsigned int u) { return __uint_as_float(u & 0xffff0000u); }

// ---------------- prep: m1/m2 embeddings + effective inception taps ----------------
__global__ __launch_bounds__(256) void prep_kernel(
    const float* __restrict__ e1, const float* __restrict__ e2,
    const float* __restrict__ gw1, const float* __restrict__ gb1,
    const float* __restrict__ gw2, const float* __restrict__ gb2,
    const float* __restrict__ pw, const float* __restrict__ pb,
    const float* __restrict__ tw2, const float* __restrict__ tb2,
    const float* __restrict__ tw3, const float* __restrict__ tb3,
    const float* __restrict__ tw6, const float* __restrict__ tb6,
    const float* __restrict__ tw7, const float* __restrict__ tb7,
    float* __restrict__ ws)
{
    int n = blockIdx.x * blockDim.x + threadIdx.x;
    if (n < NN) {
        float a1[16], a2[16];
        #pragma unroll
        for (int o = 0; o < 16; ++o) { a1[o] = gb1[o]; a2[o] = gb2[o]; }
        #pragma unroll
        for (int i = 0; i < 16; ++i) {
            float u = e1[n*16+i], v = e2[n*16+i];
            #pragma unroll
            for (int o = 0; o < 16; ++o) {
                a1[o] += u * gw1[i*16+o];
                a2[o] += v * gw2[i*16+o];
            }
        }
        #pragma unroll
        for (int o = 0; o < 16; ++o) {
            ws[OFF_M1 + n*16+o] = tanhf(1.5f*a1[o]);
            ws[OFF_M2 + n*16+o] = tanhf(1.5f*a2[o]);
        }
    }
    if (blockIdx.x == 0 && threadIdx.x < 16) {
        int c = threadIdx.x;
        int br = c >> 2, oc = c & 3;
        const float* tw; const float* tb; int k;
        if (br == 0)      { tw = tw2; tb = tb2; k = 2; }
        else if (br == 1) { tw = tw3; tb = tb3; k = 3; }
        else if (br == 2) { tw = tw6; tb = tb6; k = 6; }
        else              { tw = tw7; tb = tb7; k = 7; }
        for (int d = 0; d < 7; ++d) ws[OFF_EW + c*7 + d] = 0.f;
        float ebv = tb[oc];
        for (int j = 0; j < k; ++j) {
            float s = 0.f, sb = 0.f;
            for (int ic = 0; ic < 16; ++ic) {
                float w = tw[(oc*16+ic)*k + j];
                s  += w * pw[ic];
                sb += w * pb[ic];
            }
            ws[OFF_EW + c*7 + (7-k+j)] = s;
            ebv += sb;
        }
        ws[OFF_EB + c] = ebv;
    }
}

// ---------------- graph: scores in registers + shuffle-argmax top-12 ----------------
__global__ __launch_bounds__(256) void graph_kernel(
    const float* __restrict__ m1, const float* __restrict__ m2,
    float* __restrict__ adjw, int* __restrict__ adji)
{
    int v = blockIdx.x;
    int tid = threadIdx.x;
    __shared__ float wv4[4];
    __shared__ int   wi4[4];
    __shared__ int   bcast_i;
    __shared__ float m1v[16], m2v[16];
    if (tid < 16) { m1v[tid] = m1[v*16+tid]; m2v[tid] = m2[v*16+tid]; }
    __syncthreads();
    const float4* m1f = (const float4*)m1;
    const float4* m2f = (const float4*)m2;
    float sreg[6];
    #pragma unroll
    for (int u = 0; u < 6; ++u) {
        int j = tid + 256*u;
        float a = -1.f;
        if (j < NN) {
            float d = 0.f;
            #pragma unroll
            for (int q = 0; q < 4; ++q) {
                float4 r2 = m2f[j*4+q];
                float4 r1 = m1f[j*4+q];
                d += m1v[4*q+0]*r2.x - m2v[4*q+0]*r1.x;
                d += m1v[4*q+1]*r2.y - m2v[4*q+1]*r1.y;
                d += m1v[4*q+2]*r2.z - m2v[4*q+2]*r1.z;
                d += m1v[4*q+3]*r2.w - m2v[4*q+3]*r1.w;
            }
            float t = tanhf(1.5f*d);
            a = t > 0.f ? t : 0.f;
        }
        sreg[u] = a;
    }
    float lb = -1.f; int li = NN;
    #pragma unroll
    for (int u = 0; u < 6; ++u) {
        int j = tid + 256*u;
        if (j < NN && sreg[u] > lb) { lb = sreg[u]; li = j; }
    }
    const int wid = tid >> 6;
    for (int it = 0; it < TOPKK; ++it) {
        float bv = lb; int bi = li;
        #pragma unroll
        for (int off = 32; off > 0; off >>= 1) {
            float ov = __shfl_down(bv, off);
            int   oi = __shfl_down(bi, off);
            if (ov > bv || (ov == bv && oi < bi)) { bv = ov; bi = oi; }
        }
        if ((tid & 63) == 0) { wv4[wid] = bv; wi4[wid] = bi; }
        __syncthreads();
        if (tid == 0) {
            #pragma unroll
            for (int w = 1; w < 4; ++w) {
                float ov = wv4[w]; int oi = wi4[w];
                if (ov > bv || (ov == bv && oi < bi)) { bv = ov; bi = oi; }
            }
            adjw[v*13+it] = bv;
            adji[v*13+it] = bi;
            bcast_i = bi;
        }
        __syncthreads();
        int win = bcast_i;
        if (li == win) {
            #pragma unroll
            for (int u = 0; u < 6; ++u)
                if (tid + 256*u == win) sreg[u] = -1.f;
            lb = -1.f; li = NN;
            #pragma unroll
            for (int u = 0; u < 6; ++u) {
                int j = tid + 256*u;
                if (j < NN && sreg[u] > lb) { lb = sreg[u]; li = j; }
            }
        }
    }
    if (tid == 0) {
        float s = 1.f;
        #pragma unroll
        for (int it = 0; it < TOPKK; ++it) s += adjw[v*13+it];
        float inv = 1.f/s;
        #pragma unroll
        for (int it = 0; it < TOPKK; ++it) adjw[v*13+it] *= inv;
        adji[v*13+12] = v;
        adjw[v*13+12] = inv;   // normalized self-loop
    }
}

// ---------------- main: 3 phases/t, NO cross-phase register state ----------------
// The t-accumulator lives in global memory (exclusive per-block region, L2-resident):
// phase C/D ends with part += r16 (plain store on first t — handles 0xAA poison).
// This removes the long-live-range registers the allocator was spilling ~1 GB on.
__global__ __launch_bounds__(NTH, 3) void main_kernel(
    const float* __restrict__ x,
    const float* __restrict__ ew, const float* __restrict__ eb,
    const float* __restrict__ adjw, const int* __restrict__ adji,
    float* __restrict__ part,
    const float* __restrict__ mw, const float* __restrict__ mb,
    const float* __restrict__ rw1, const float* __restrict__ rb1)
{
    // SoA by row: row r holds channels 8r..8r+7 (uint4 = 8 bf16), contiguous in v.
    __shared__ uint4 h1b[2][NN];   // 48000 B : h1 bf16
    __shared__ uint4 p1b[2][NN];   // 48000 B : hop1 bf16

    const int tid = threadIdx.x;
    const int b = blockIdx.x >> 5;
    const int g = blockIdx.x & 31;
    const int t0 = (g*TLEN) >> 5;
    const int t1 = ((g+1)*TLEN) >> 5;

    for (int t = t0; t < t1; ++t) {
        // ---- Phase A: 7-tap conv -> h1 (bf16 LDS) ----
        #pragma unroll
        for (int s = 0; s < SN; ++s) {
            int v = tid + NTH*s;
            if (v < NN) {
                float xv[7];
                #pragma unroll
                for (int d = 0; d < 7; ++d) xv[d] = x[(b*TIN + t + d)*NN + v];
                float h[16];
                #pragma unroll
                for (int c = 0; c < 16; ++c) {
                    float a = eb[c];
                    #pragma unroll
                    for (int d = 0; d < 7; ++d) a += ew[c*7+d]*xv[d];
                    h[c] = a > 0.f ? a : 0.f;
                }
                h1b[0][v] = make_uint4(pack2(h[0],h[1]), pack2(h[2],h[3]), pack2(h[4],h[5]), pack2(h[6],h[7]));
                h1b[1][v] = make_uint4(pack2(h[8],h[9]), pack2(h[10],h[11]), pack2(h[12],h[13]), pack2(h[14],h[15]));
            }
        }
        __syncthreads();
        // ---- Phase B: hop1 = 0.2*h1own + 0.8*A@h1 -> p1b ----
        #pragma unroll
        for (int s = 0; s < SN; ++s) {
            int v = tid + NTH*s;
            if (v < NN) {
                float hp[16];
                {
                    uint4 a0 = h1b[0][v], a1 = h1b[1][v];
                    unsigned int uu[8] = {a0.x,a0.y,a0.z,a0.w,a1.x,a1.y,a1.z,a1.w};
                    #pragma unroll
                    for (int i = 0; i < 8; ++i) { hp[2*i] = 0.2f*unlo(uu[i]); hp[2*i+1] = 0.2f*unhi(uu[i]); }
                }
                int base = v*13;
                #pragma unroll
                for (int j = 0; j < 13; ++j) {
                    int nb = adji[base+j];
                    float w = 0.8f*adjw[base+j];
                    uint4 b0 = h1b[0][nb], b1 = h1b[1][nb];
                    unsigned int uu[8] = {b0.x,b0.y,b0.z,b0.w,b1.x,b1.y,b1.z,b1.w};
                    #pragma unroll
                    for (int i = 0; i < 8; ++i) { hp[2*i] += w*unlo(uu[i]); hp[2*i+1] += w*unhi(uu[i]); }
                }
                p1b[0][v] = make_uint4(pack2(hp[0],hp[1]), pack2(hp[2],hp[3]), pack2(hp[4],hp[5]), pack2(hp[6],hp[7]));
                p1b[1][v] = make_uint4(pack2(hp[8],hp[9]), pack2(hp[10],hp[11]), pack2(hp[12],hp[13]), pack2(hp[14],hp[15]));
            }
        }
        __syncthreads();
        // ---- Phase C/D: hop2 gather (regs) + mw folds + rw1 ; accumulate to global ----
        #pragma unroll
        for (int s = 0; s < SN; ++s) {
            int v = tid + NTH*s;
            if (v < NN) {
                float y16[16];
                #pragma unroll
                for (int o = 0; o < 16; ++o) y16[o] = mb[o];
                float hop2[16];
                // own h1: hop2 base + fold mw[:,0:16]
                {
                    uint4 a0 = h1b[0][v], a1 = h1b[1][v];
                    unsigned int uu[8] = {a0.x,a0.y,a0.z,a0.w,a1.x,a1.y,a1.z,a1.w};
                    #pragma unroll
                    for (int i = 0; i < 8; ++i) {
                        float f0 = unlo(uu[i]), f1 = unhi(uu[i]);
                        hop2[2*i] = 0.2f*f0; hop2[2*i+1] = 0.2f*f1;
                        #pragma unroll
                        for (int o = 0; o < 16; ++o)
                            y16[o] += mw[o*48 + 2*i]*f0 + mw[o*48 + 2*i+1]*f1;
                    }
                }
                // own hop1: fold mw[:,16:32]
                {
                    uint4 a0 = p1b[0][v], a1 = p1b[1][v];
                    unsigned int uu[8] = {a0.x,a0.y,a0.z,a0.w,a1.x,a1.y,a1.z,a1.w};
                    #pragma unroll
                    for (int i = 0; i < 8; ++i) {
                        float f0 = unlo(uu[i]), f1 = unhi(uu[i]);
                        #pragma unroll
                        for (int o = 0; o < 16; ++o)
                            y16[o] += mw[o*48+16 + 2*i]*f0 + mw[o*48+16 + 2*i+1]*f1;
                    }
                }
                // gather hop2 from hop1
                int base = v*13;
                #pragma unroll
                for (int j = 0; j < 13; ++j) {
                    int nb = adji[base+j];
                    float w = 0.8f*adjw[base+j];
                    uint4 b0 = p1b[0][nb], b1 = p1b[1][nb];
                    unsigned int uu[8] = {b0.x,b0.y,b0.z,b0.w,b1.x,b1.y,b1.z,b1.w};
                    #pragma unroll
                    for (int i = 0; i < 8; ++i) { hop2[2*i] += w*unlo(uu[i]); hop2[2*i+1] += w*unhi(uu[i]); }
                }
                // fold mw[:,32:48] + relu
                #pragma unroll
                for (int o = 0; o < 16; ++o) {
                    float a = y16[o];
                    #pragma unroll
                    for (int c = 0; c < 16; ++c) a += mw[o*48+32+c]*hop2[c];
                    y16[o] = a > 0.f ? a : 0.f;
                }
                // r16 = relu(rw1@y16 + rb1) ; accumulate into exclusive global region
                float r16[16];
                #pragma unroll
                for (int o = 0; o < 16; ++o) {
                    float a = rb1[o];
                    #pragma unroll
                    for (int i = 0; i < 16; ++i) a += rw1[o*16+i]*y16[i];
                    r16[o] = a > 0.f ? a : 0.f;
                }
                size_t pbase = ((size_t)(b*NG + g)*16)*NN + v;
                if (t == t0) {
                    #pragma unroll
                    for (int o = 0; o < 16; ++o) part[pbase + (size_t)o*NN] = r16[o];
                } else {
                    #pragma unroll
                    for (int o = 0; o < 16; ++o) part[pbase + (size_t)o*NN] += r16[o];
                }
            }
        }
        __syncthreads();   // C/D reads h1b/p1b; next-t A/B overwrite them
    }
}

// ---------------- reduce: sum 32 t-group partials, apply rw2/rb2, mean ----------------
__global__ __launch_bounds__(256) void reduce_kernel(const float* __restrict__ part,
                                                     const float* __restrict__ rw2,
                                                     const float* __restrict__ rb2,
                                                     float* __restrict__ out)
{
    int idx = blockIdx.x*256 + threadIdx.x;   // idx over b*NN + v
    if (idx >= BB*NN) return;
    int v = idx % NN;
    int b = idx / NN;
    float s16[16];
    #pragma unroll
    for (int c = 0; c < 16; ++c) s16[c] = 0.f;
    for (int g = 0; g < NG; ++g) {
        #pragma unroll
        for (int c = 0; c < 16; ++c)
            s16[c] += part[((b*NG + g)*16 + c)*NN + v];
    }
    #pragma unroll
    for (int c = 0; c < 16; ++c) s16[c] *= (1.0f/TLEN);
    #pragma unroll
    for (int o = 0; o < TOUTC; ++o) {
        float a = rb2[o];
        #pragma unroll
        for (int c = 0; c < 16; ++c) a += rw2[o*16+c]*s16[c];
        out[(b*TOUTC + o)*NN + v] = a;
    }
}

extern "C" void kernel_launch(void* const* d_in, const int* in_sizes, int n_in,
                              void* d_out, int out_size, void* d_ws, size_t ws_size,
                              hipStream_t stream)
{
    const float* x   = (const float*)d_in[0];
    const float* pw  = (const float*)d_in[1];
    const float* pb  = (const float*)d_in[2];
    const float* tw2 = (const float*)d_in[3];
    const float* tb2 = (const float*)d_in[4];
    const float* tw3 = (const float*)d_in[5];
    const float* tb3 = (const float*)d_in[6];
    const float* tw6 = (const float*)d_in[7];
    const float* tb6 = (const float*)d_in[8];
    const float* tw7 = (const float*)d_in[9];
    const float* tb7 = (const float*)d_in[10];
    const float* e1  = (const float*)d_in[11];
    const float* e2  = (const float*)d_in[12];
    const float* gw1 = (const float*)d_in[13];
    const float* gb1 = (const float*)d_in[14];
    const float* gw2 = (const float*)d_in[15];
    const float* gb2 = (const float*)d_in[16];
    const float* mw  = (const float*)d_in[17];
    const float* mb  = (const float*)d_in[18];
    const float* rw1 = (const float*)d_in[19];
    const float* rb1 = (const float*)d_in[20];
    const float* rw2 = (const float*)d_in[21];
    const float* rb2 = (const float*)d_in[22];
    float* ws  = (float*)d_ws;
    float* out = (float*)d_out;

    prep_kernel<<<(NN + 255)/256, 256, 0, stream>>>(e1,e2,gw1,gb1,gw2,gb2,pw,pb,
                                                    tw2,tb2,tw3,tb3,tw6,tb6,tw7,tb7, ws);
    graph_kernel<<<NN, 256, 0, stream>>>(ws + OFF_M1, ws + OFF_M2,
                                         ws + OFF_ADJW, (int*)ws + OFF_ADJI);
    main_kernel<<<BB*NG, NTH, 0, stream>>>(x, ws + OFF_EW, ws + OFF_EB,
                                           ws + OFF_ADJW, (const int*)ws + OFF_ADJI,
                                           ws + OFF_PART, mw, mb, rw1, rb1);
    reduce_kernel<<<(BB*NN + 255)/256, 256, 0, stream>>>(ws + OFF_PART, rw2, rb2, out);
}

// Round 9
// 519.289 us; speedup vs baseline: 2.6142x; 1.2523x over previous
//
#include <hip/hip_runtime.h>

#define BB 8
#define TIN 168
#define NN 1500
#define TOUTC 24
#define TLEN 162
#define NG 32
#define NTH 768
#define SN 2
#define TOPKK 12

// workspace offsets (in 4-byte elements)
#define OFF_M1   0
#define OFF_M2   24000
#define OFF_EW   48000
#define OFF_EB   48112
#define OFF_ADJW 48128
#define OFF_ADJI 67628
#define OFF_PART 87136
// part is [b][g][c=16][v] : 8*32*16*1500 floats = 24.58 MB
// total ws need: (87136 + 6144000)*4 = 24,924,544 bytes

__device__ __forceinline__ unsigned short f2bf(float f) {
    unsigned int u = __float_as_uint(f);
    unsigned int r = (u + 0x7fffu + ((u >> 16) & 1u)) >> 16;
    return (unsigned short)r;
}
__device__ __forceinline__ unsigned int pack2(float lo, float hi) {
    return (unsigned int)f2bf(lo) | ((unsigned int)f2bf(hi) << 16);
}
__device__ __forceinline__ float unlo(unsigned int u) { return __uint_as_float(u << 16); }
__device__ __forceinline__ float unhi(unsigned int u) { return __uint_as_float(u & 0xffff0000u); }

// ---------------- prep: m1/m2 embeddings + effective inception taps ----------------
__global__ __launch_bounds__(256) void prep_kernel(
    const float* __restrict__ e1, const float* __restrict__ e2,
    const float* __restrict__ gw1, const float* __restrict__ gb1,
    const float* __restrict__ gw2, const float* __restrict__ gb2,
    const float* __restrict__ pw, const float* __restrict__ pb,
    const float* __restrict__ tw2, const float* __restrict__ tb2,
    const float* __restrict__ tw3, const float* __restrict__ tb3,
    const float* __restrict__ tw6, const float* __restrict__ tb6,
    const float* __restrict__ tw7, const float* __restrict__ tb7,
    float* __restrict__ ws)
{
    int n = blockIdx.x * blockDim.x + threadIdx.x;
    if (n < NN) {
        float a1[16], a2[16];
        #pragma unroll
        for (int o = 0; o < 16; ++o) { a1[o] = gb1[o]; a2[o] = gb2[o]; }
        #pragma unroll
        for (int i = 0; i < 16; ++i) {
            float u = e1[n*16+i], v = e2[n*16+i];
            #pragma unroll
            for (int o = 0; o < 16; ++o) {
                a1[o] += u * gw1[i*16+o];
                a2[o] += v * gw2[i*16+o];
            }
        }
        #pragma unroll
        for (int o = 0; o < 16; ++o) {
            ws[OFF_M1 + n*16+o] = tanhf(1.5f*a1[o]);
            ws[OFF_M2 + n*16+o] = tanhf(1.5f*a2[o]);
        }
    }
    if (blockIdx.x == 0 && threadIdx.x < 16) {
        int c = threadIdx.x;
        int br = c >> 2, oc = c & 3;
        const float* tw; const float* tb; int k;
        if (br == 0)      { tw = tw2; tb = tb2; k = 2; }
        else if (br == 1) { tw = tw3; tb = tb3; k = 3; }
        else if (br == 2) { tw = tw6; tb = tb6; k = 6; }
        else              { tw = tw7; tb = tb7; k = 7; }
        for (int d = 0; d < 7; ++d) ws[OFF_EW + c*7 + d] = 0.f;
        float ebv = tb[oc];
        for (int j = 0; j < k; ++j) {
            float s = 0.f, sb = 0.f;
            for (int ic = 0; ic < 16; ++ic) {
                float w = tw[(oc*16+ic)*k + j];
                s  += w * pw[ic];
                sb += w * pb[ic];
            }
            ws[OFF_EW + c*7 + (7-k+j)] = s;
            ebv += sb;
        }
        ws[OFF_EB + c] = ebv;
    }
}

// ---------------- graph: scores in registers + shuffle-argmax top-12 ----------------
__global__ __launch_bounds__(256) void graph_kernel(
    const float* __restrict__ m1, const float* __restrict__ m2,
    float* __restrict__ adjw, int* __restrict__ adji)
{
    int v = blockIdx.x;
    int tid = threadIdx.x;
    __shared__ float wv4[4];
    __shared__ int   wi4[4];
    __shared__ int   bcast_i;
    __shared__ float m1v[16], m2v[16];
    if (tid < 16) { m1v[tid] = m1[v*16+tid]; m2v[tid] = m2[v*16+tid]; }
    __syncthreads();
    const float4* m1f = (const float4*)m1;
    const float4* m2f = (const float4*)m2;
    float sreg[6];
    #pragma unroll
    for (int u = 0; u < 6; ++u) {
        int j = tid + 256*u;
        float a = -1.f;
        if (j < NN) {
            float d = 0.f;
            #pragma unroll
            for (int q = 0; q < 4; ++q) {
                float4 r2 = m2f[j*4+q];
                float4 r1 = m1f[j*4+q];
                d += m1v[4*q+0]*r2.x - m2v[4*q+0]*r1.x;
                d += m1v[4*q+1]*r2.y - m2v[4*q+1]*r1.y;
                d += m1v[4*q+2]*r2.z - m2v[4*q+2]*r1.z;
                d += m1v[4*q+3]*r2.w - m2v[4*q+3]*r1.w;
            }
            float t = tanhf(1.5f*d);
            a = t > 0.f ? t : 0.f;
        }
        sreg[u] = a;
    }
    float lb = -1.f; int li = NN;
    #pragma unroll
    for (int u = 0; u < 6; ++u) {
        int j = tid + 256*u;
        if (j < NN && sreg[u] > lb) { lb = sreg[u]; li = j; }
    }
    const int wid = tid >> 6;
    for (int it = 0; it < TOPKK; ++it) {
        float bv = lb; int bi = li;
        #pragma unroll
        for (int off = 32; off > 0; off >>= 1) {
            float ov = __shfl_down(bv, off);
            int   oi = __shfl_down(bi, off);
            if (ov > bv || (ov == bv && oi < bi)) { bv = ov; bi = oi; }
        }
        if ((tid & 63) == 0) { wv4[wid] = bv; wi4[wid] = bi; }
        __syncthreads();
        if (tid == 0) {
            #pragma unroll
            for (int w = 1; w < 4; ++w) {
                float ov = wv4[w]; int oi = wi4[w];
                if (ov > bv || (ov == bv && oi < bi)) { bv = ov; bi = oi; }
            }
            adjw[v*13+it] = bv;
            adji[v*13+it] = bi;
            bcast_i = bi;
        }
        __syncthreads();
        int win = bcast_i;
        if (li == win) {
            #pragma unroll
            for (int u = 0; u < 6; ++u)
                if (tid + 256*u == win) sreg[u] = -1.f;
            lb = -1.f; li = NN;
            #pragma unroll
            for (int u = 0; u < 6; ++u) {
                int j = tid + 256*u;
                if (j < NN && sreg[u] > lb) { lb = sreg[u]; li = j; }
            }
        }
    }
    if (tid == 0) {
        float s = 1.f;
        #pragma unroll
        for (int it = 0; it < TOPKK; ++it) s += adjw[v*13+it];
        float inv = 1.f/s;
        #pragma unroll
        for (int it = 0; it < TOPKK; ++it) adjw[v*13+it] *= inv;
        adji[v*13+12] = v;
        adjw[v*13+12] = inv;   // normalized self-loop
    }
}

// ---------------- main: 3 phases/t, no cross-phase regs, s-loops SERIALIZED ----------------
// #pragma unroll 1 on the s-loops: with the loop unrolled, the scheduler
// interleaved both s-iterations per phase, doubling live values past the
// 84-VGPR allocation -> per-phase spill storms (~700 MB phantom HBM traffic).
// TLP (12 waves/CU) hides LDS latency; the interleave bought nothing.
__global__ __launch_bounds__(NTH, 3) void main_kernel(
    const float* __restrict__ x,
    const float* __restrict__ ew, const float* __restrict__ eb,
    const float* __restrict__ adjw, const int* __restrict__ adji,
    float* __restrict__ part,
    const float* __restrict__ mw, const float* __restrict__ mb,
    const float* __restrict__ rw1, const float* __restrict__ rb1)
{
    // SoA by row: row r holds channels 8r..8r+7 (uint4 = 8 bf16), contiguous in v.
    __shared__ uint4 h1b[2][NN];   // 48000 B : h1 bf16
    __shared__ uint4 p1b[2][NN];   // 48000 B : hop1 bf16

    const int tid = threadIdx.x;
    const int b = blockIdx.x >> 5;
    const int g = blockIdx.x & 31;
    const int t0 = (g*TLEN) >> 5;
    const int t1 = ((g+1)*TLEN) >> 5;

    for (int t = t0; t < t1; ++t) {
        // ---- Phase A: 7-tap conv -> h1 (bf16 LDS) ----
        #pragma unroll 1
        for (int s = 0; s < SN; ++s) {
            int v = tid + NTH*s;
            if (v < NN) {
                float xv[7];
                #pragma unroll
                for (int d = 0; d < 7; ++d) xv[d] = x[(b*TIN + t + d)*NN + v];
                float h[16];
                #pragma unroll
                for (int c = 0; c < 16; ++c) {
                    float a = eb[c];
                    #pragma unroll
                    for (int d = 0; d < 7; ++d) a += ew[c*7+d]*xv[d];
                    h[c] = a > 0.f ? a : 0.f;
                }
                h1b[0][v] = make_uint4(pack2(h[0],h[1]), pack2(h[2],h[3]), pack2(h[4],h[5]), pack2(h[6],h[7]));
                h1b[1][v] = make_uint4(pack2(h[8],h[9]), pack2(h[10],h[11]), pack2(h[12],h[13]), pack2(h[14],h[15]));
            }
        }
        __syncthreads();
        // ---- Phase B: hop1 = 0.2*h1own + 0.8*A@h1 -> p1b ----
        #pragma unroll 1
        for (int s = 0; s < SN; ++s) {
            int v = tid + NTH*s;
            if (v < NN) {
                float hp[16];
                {
                    uint4 a0 = h1b[0][v], a1 = h1b[1][v];
                    unsigned int uu[8] = {a0.x,a0.y,a0.z,a0.w,a1.x,a1.y,a1.z,a1.w};
                    #pragma unroll
                    for (int i = 0; i < 8; ++i) { hp[2*i] = 0.2f*unlo(uu[i]); hp[2*i+1] = 0.2f*unhi(uu[i]); }
                }
                int base = v*13;
                #pragma unroll
                for (int j = 0; j < 13; ++j) {
                    int nb = adji[base+j];
                    float w = 0.8f*adjw[base+j];
                    uint4 b0 = h1b[0][nb], b1 = h1b[1][nb];
                    unsigned int uu[8] = {b0.x,b0.y,b0.z,b0.w,b1.x,b1.y,b1.z,b1.w};
                    #pragma unroll
                    for (int i = 0; i < 8; ++i) { hp[2*i] += w*unlo(uu[i]); hp[2*i+1] += w*unhi(uu[i]); }
                }
                p1b[0][v] = make_uint4(pack2(hp[0],hp[1]), pack2(hp[2],hp[3]), pack2(hp[4],hp[5]), pack2(hp[6],hp[7]));
                p1b[1][v] = make_uint4(pack2(hp[8],hp[9]), pack2(hp[10],hp[11]), pack2(hp[12],hp[13]), pack2(hp[14],hp[15]));
            }
        }
        __syncthreads();
        // ---- Phase C/D: hop2 gather (regs) + mw folds + rw1 ; accumulate to global ----
        #pragma unroll 1
        for (int s = 0; s < SN; ++s) {
            int v = tid + NTH*s;
            if (v < NN) {
                float y16[16];
                #pragma unroll
                for (int o = 0; o < 16; ++o) y16[o] = mb[o];
                float hop2[16];
                // own h1: hop2 base + fold mw[:,0:16]
                {
                    uint4 a0 = h1b[0][v], a1 = h1b[1][v];
                    unsigned int uu[8] = {a0.x,a0.y,a0.z,a0.w,a1.x,a1.y,a1.z,a1.w};
                    #pragma unroll
                    for (int i = 0; i < 8; ++i) {
                        float f0 = unlo(uu[i]), f1 = unhi(uu[i]);
                        hop2[2*i] = 0.2f*f0; hop2[2*i+1] = 0.2f*f1;
                        #pragma unroll
                        for (int o = 0; o < 16; ++o)
                            y16[o] += mw[o*48 + 2*i]*f0 + mw[o*48 + 2*i+1]*f1;
                    }
                }
                // own hop1: fold mw[:,16:32]
                {
                    uint4 a0 = p1b[0][v], a1 = p1b[1][v];
                    unsigned int uu[8] = {a0.x,a0.y,a0.z,a0.w,a1.x,a1.y,a1.z,a1.w};
                    #pragma unroll
                    for (int i = 0; i < 8; ++i) {
                        float f0 = unlo(uu[i]), f1 = unhi(uu[i]);
                        #pragma unroll
                        for (int o = 0; o < 16; ++o)
                            y16[o] += mw[o*48+16 + 2*i]*f0 + mw[o*48+16 + 2*i+1]*f1;
                    }
                }
                // gather hop2 from hop1
                int base = v*13;
                #pragma unroll
                for (int j = 0; j < 13; ++j) {
                    int nb = adji[base+j];
                    float w = 0.8f*adjw[base+j];
                    uint4 b0 = p1b[0][nb], b1 = p1b[1][nb];
                    unsigned int uu[8] = {b0.x,b0.y,b0.z,b0.w,b1.x,b1.y,b1.z,b1.w};
                    #pragma unroll
                    for (int i = 0; i < 8; ++i) { hop2[2*i] += w*unlo(uu[i]); hop2[2*i+1] += w*unhi(uu[i]); }
                }
                // fold mw[:,32:48] + relu
                #pragma unroll
                for (int o = 0; o < 16; ++o) {
                    float a = y16[o];
                    #pragma unroll
                    for (int c = 0; c < 16; ++c) a += mw[o*48+32+c]*hop2[c];
                    y16[o] = a > 0.f ? a : 0.f;
                }
                // r16 = relu(rw1@y16 + rb1) ; accumulate into exclusive global region
                float r16[16];
                #pragma unroll
                for (int o = 0; o < 16; ++o) {
                    float a = rb1[o];
                    #pragma unroll
                    for (int i = 0; i < 16; ++i) a += rw1[o*16+i]*y16[i];
                    r16[o] = a > 0.f ? a : 0.f;
                }
                size_t pbase = ((size_t)(b*NG + g)*16)*NN + v;
                if (t == t0) {
                    #pragma unroll
                    for (int o = 0; o < 16; ++o) part[pbase + (size_t)o*NN] = r16[o];
                } else {
                    #pragma unroll
                    for (int o = 0; o < 16; ++o) part[pbase + (size_t)o*NN] += r16[o];
                }
            }
        }
        __syncthreads();   // C/D reads h1b/p1b; next-t A/B overwrite them
    }
}

// ---------------- reduce: sum 32 t-group partials, apply rw2/rb2, mean ----------------
__global__ __launch_bounds__(256) void reduce_kernel(const float* __restrict__ part,
                                                     const float* __restrict__ rw2,
                                                     const float* __restrict__ rb2,
                                                     float* __restrict__ out)
{
    int idx = blockIdx.x*256 + threadIdx.x;   // idx over b*NN + v
    if (idx >= BB*NN) return;
    int v = idx % NN;
    int b = idx / NN;
    float s16[16];
    #pragma unroll
    for (int c = 0; c < 16; ++c) s16[c] = 0.f;
    for (int g = 0; g < NG; ++g) {
        #pragma unroll
        for (int c = 0; c < 16; ++c)
            s16[c] += part[((b*NG + g)*16 + c)*NN + v];
    }
    #pragma unroll
    for (int c = 0; c < 16; ++c) s16[c] *= (1.0f/TLEN);
    #pragma unroll
    for (int o = 0; o < TOUTC; ++o) {
        float a = rb2[o];
        #pragma unroll
        for (int c = 0; c < 16; ++c) a += rw2[o*16+c]*s16[c];
        out[(b*TOUTC + o)*NN + v] = a;
    }
}

extern "C" void kernel_launch(void* const* d_in, const int* in_sizes, int n_in,
                              void* d_out, int out_size, void* d_ws, size_t ws_size,
                              hipStream_t stream)
{
    const float* x   = (const float*)d_in[0];
    const float* pw  = (const float*)d_in[1];
    const float* pb  = (const float*)d_in[2];
    const float* tw2 = (const float*)d_in[3];
    const float* tb2 = (const float*)d_in[4];
    const float* tw3 = (const float*)d_in[5];
    const float* tb3 = (const float*)d_in[6];
    const float* tw6 = (const float*)d_in[7];
    const float* tb6 = (const float*)d_in[8];
    const float* tw7 = (const float*)d_in[9];
    const float* tb7 = (const float*)d_in[10];
    const float* e1  = (const float*)d_in[11];
    const float* e2  = (const float*)d_in[12];
    const float* gw1 = (const float*)d_in[13];
    const float* gb1 = (const float*)d_in[14];
    const float* gw2 = (const float*)d_in[15];
    const float* gb2 = (const float*)d_in[16];
    const float* mw  = (const float*)d_in[17];
    const float* mb  = (const float*)d_in[18];
    const float* rw1 = (const float*)d_in[19];
    const float* rb1 = (const float*)d_in[20];
    const float* rw2 = (const float*)d_in[21];
    const float* rb2 = (const float*)d_in[22];
    float* ws  = (float*)d_ws;
    float* out = (float*)d_out;

    prep_kernel<<<(NN + 255)/256, 256, 0, stream>>>(e1,e2,gw1,gb1,gw2,gb2,pw,pb,
                                                    tw2,tb2,tw3,tb3,tw6,tb6,tw7,tb7, ws);
    graph_kernel<<<NN, 256, 0, stream>>>(ws + OFF_M1, ws + OFF_M2,
                                         ws + OFF_ADJW, (int*)ws + OFF_ADJI);
    main_kernel<<<BB*NG, NTH, 0, stream>>>(x, ws + OFF_EW, ws + OFF_EB,
                                           ws + OFF_ADJW, (const int*)ws + OFF_ADJI,
                                           ws + OFF_PART, mw, mb, rw1, rb1);
    reduce_kernel<<<(BB*NN + 255)/256, 256, 0, stream>>>(ws + OFF_PART, rw2, rb2, out);
}